// Round 1
// baseline (342.445 us; speedup 1.0000x reference)
//
#include <hip/hip_runtime.h>
#include <hip/hip_cooperative_groups.h>
#include <math.h>

namespace cg = cooperative_groups;

#define N_NODES 2048
#define N1S 36   // padded n1 row stride (16B-aligned rows)
#define NBLK 512

__device__ __forceinline__ float invdeg(int j) { return j > 0 ? 1.0f / (float)j : 0.0f; }

// Single cooperative kernel; phases separated by grid.sync().
// P1: n1 (cos-sim prefix scans + centroid |diff| sums)
// P2: h1 = h@Ws1 + n1@Wn1 + b1 (wave-per-node) + column-major copy h1T
// P3: per-feature exclusive scan of h1 columns -> n2
// P4: h2 -> A = h2@Wm1[:32], Bm = h2@Wm1[32:]+bm1
// P5: per-edge head, logit-difference form, compact triangular tiles
__global__ __launch_bounds__(256, 2) void k_fused(
    const float* __restrict__ x, const float* __restrict__ cent,
    const float* __restrict__ Ws1, const float* __restrict__ Wn1,
    const float* __restrict__ b1, const float* __restrict__ Ws2,
    const float* __restrict__ Wn2, const float* __restrict__ b2,
    const float* __restrict__ Wm1, const float* __restrict__ bm1,
    const float* __restrict__ Wm2, const float* __restrict__ bm2,
    float* __restrict__ n1, float* __restrict__ h1, float* __restrict__ h1T,
    float* __restrict__ n2, float* __restrict__ A, float* __restrict__ Bm,
    float2* __restrict__ out) {
  cg::grid_group grid = cg::this_grid();
  __shared__ float smem[6144];  // 24 KB, reused across phases
  const int tid = threadIdx.x;
  const int bx = blockIdx.x;

  // ---------------- P1: edge-feature aggregates -> n1 ----------------
  if (bx < 32) {
    // per-feature exclusive scan of x[i,f]^2/||x_i||
    float* invn_s = smem;       // 2048 floats
    float* sc = smem + 2048;    // 256 floats
    const int f = bx;
    for (int r = 0; r < 8; ++r) {
      int n = tid + 256 * r;
      const float4* xp = (const float4*)(x + n * 32);
      float s = 0.f;
#pragma unroll
      for (int q = 0; q < 8; ++q) {
        float4 v = xp[q];
        s += v.x * v.x + v.y * v.y + v.z * v.z + v.w * v.w;
      }
      invn_s[n] = rsqrtf(s);
    }
    __syncthreads();
    float sv[8], xv[8];
    float ts = 0.f;
#pragma unroll
    for (int r = 0; r < 8; ++r) {
      int i = tid * 8 + r;
      float xf = x[i * 32 + f];
      xv[r] = xf;
      float s = xf * xf * invn_s[i];
      sv[r] = s;
      ts += s;
    }
    sc[tid] = ts;
    __syncthreads();
    for (int off = 1; off < 256; off <<= 1) {
      float v = (tid >= off) ? sc[tid - off] : 0.f;
      __syncthreads();
      sc[tid] += v;
      __syncthreads();
    }
    float P = sc[tid] - ts;  // exclusive prefix of thread-chunk sums
#pragma unroll
    for (int r = 0; r < 8; ++r) {
      int i = tid * 8 + r;
      n1[i * N1S + f] = P * xv[r] * invn_s[i] * invdeg(i);
      P += sv[r];
    }
  } else if (bx < 288) {
    // centroid part: wave w handles j in {w, 2047-w} (balanced)
    float* cs = smem;  // 6144 floats
    const float4* cp = (const float4*)cent;
    float4* csp = (float4*)cs;
#pragma unroll
    for (int q = 0; q < 6; ++q) csp[tid + 256 * q] = cp[tid + 256 * q];
    __syncthreads();
    const int w = (bx - 32) * 4 + (tid >> 6);  // 0..1023
    const int lane = tid & 63;
#pragma unroll
    for (int pick = 0; pick < 2; ++pick) {
      const int j = pick ? (2047 - w) : w;
      const float cj0 = cs[j * 3 + 0], cj1 = cs[j * 3 + 1], cj2 = cs[j * 3 + 2];
      float s0 = 0.f, s1 = 0.f, s2 = 0.f;
      for (int i = lane; i < j; i += 64) {
        float c0 = cs[i * 3 + 0], c1 = cs[i * 3 + 1], c2 = cs[i * 3 + 2];
        s0 += c0 * fabsf(c0 - cj0);
        s1 += c1 * fabsf(c1 - cj1);
        s2 += c2 * fabsf(c2 - cj2);
      }
#pragma unroll
      for (int d = 32; d > 0; d >>= 1) {
        s0 += __shfl_down(s0, d);
        s1 += __shfl_down(s1, d);
        s2 += __shfl_down(s2, d);
      }
      if (lane == 0) {
        float idg = invdeg(j);
        n1[j * N1S + 32] = s0 * idg;
        n1[j * N1S + 33] = s1 * idg;
        n1[j * N1S + 34] = s2 * idg;
      }
    }
  }
  grid.sync();

  // ---------------- P2: h1 (wave-per-node) ----------------
  {
    const int n = __builtin_amdgcn_readfirstlane(bx * 4 + (tid >> 6));  // 0..2047
    const int o = tid & 63;
    float acc = b1[o];
    const float4* xr = (const float4*)(x + n * 32);
    const float4* nr = (const float4*)(n1 + n * N1S);
#pragma unroll
    for (int q = 0; q < 8; ++q) {
      float4 xv = xr[q];
      float4 nv = nr[q];
      acc += xv.x * Ws1[(4 * q + 0) * 64 + o] + nv.x * Wn1[(4 * q + 0) * 64 + o];
      acc += xv.y * Ws1[(4 * q + 1) * 64 + o] + nv.y * Wn1[(4 * q + 1) * 64 + o];
      acc += xv.z * Ws1[(4 * q + 2) * 64 + o] + nv.z * Wn1[(4 * q + 2) * 64 + o];
      acc += xv.w * Ws1[(4 * q + 3) * 64 + o] + nv.w * Wn1[(4 * q + 3) * 64 + o];
    }
    {
      float4 nv = nr[8];  // floats 32..35 (35 is pad, unused)
      float c0 = cent[n * 3 + 0], c1 = cent[n * 3 + 1], c2 = cent[n * 3 + 2];
      acc += c0 * Ws1[32 * 64 + o] + nv.x * Wn1[32 * 64 + o];
      acc += c1 * Ws1[33 * 64 + o] + nv.y * Wn1[33 * 64 + o];
      acc += c2 * Ws1[34 * 64 + o] + nv.z * Wn1[34 * 64 + o];
    }
    h1[n * 64 + o] = acc;
    h1T[o * N_NODES + n] = acc;  // coalesced-read copy for P3
  }
  grid.sync();

  // ---------------- P3: column scans -> n2 ----------------
  if (bx < 64) {
    float* sc = smem;
    const int o = bx;
    float sv[8];
    const float4* colp = (const float4*)(h1T + o * N_NODES);
    float4 a = colp[2 * tid];
    float4 b = colp[2 * tid + 1];
    sv[0] = a.x; sv[1] = a.y; sv[2] = a.z; sv[3] = a.w;
    sv[4] = b.x; sv[5] = b.y; sv[6] = b.z; sv[7] = b.w;
    float ts = 0.f;
#pragma unroll
    for (int r = 0; r < 8; ++r) ts += sv[r];
    sc[tid] = ts;
    __syncthreads();
    for (int off = 1; off < 256; off <<= 1) {
      float v = (tid >= off) ? sc[tid - off] : 0.f;
      __syncthreads();
      sc[tid] += v;
      __syncthreads();
    }
    float P = sc[tid] - ts;
#pragma unroll
    for (int r = 0; r < 8; ++r) {
      int i = tid * 8 + r;
      n2[i * 64 + o] = P * invdeg(i);
      P += sv[r];
    }
  }
  grid.sync();

  // ---------------- P4: h2 -> A, Bm ----------------
  {
    float* h2s = smem;  // [4][32]
    const int wv = tid >> 6;
    const int lane = tid & 63;
    const int o = lane & 31;
    const int half = lane >> 5;
    const int n = __builtin_amdgcn_readfirstlane(bx * 4 + wv);
    float acc = b2[o];
#pragma unroll
    for (int f = 0; f < 64; ++f)
      acc += h1[n * 64 + f] * Ws2[f * 32 + o] + n2[n * 64 + f] * Wn2[f * 32 + o];
    h2s[wv * 32 + o] = acc;  // both halves write identical value
    __syncthreads();
    float r = half ? bm1[o] : 0.f;
#pragma unroll
    for (int f = 0; f < 32; ++f)
      r += h2s[wv * 32 + f] * Wm1[(half * 32 + f) * 32 + o];
    if (half)
      Bm[n * 32 + o] = r;
    else
      A[n * 32 + o] = r;
  }
  grid.sync();

  // ---------------- P5: edge head ----------------
  {
    float wd[32];
#pragma unroll
    for (int f = 0; f < 32; ++f)
      wd[f] = Wm2[f * 2 + 1] - Wm2[f * 2];  // uniform
    const float db = bm2[1] - bm2[0];
    // Surviving tiles (i0 < j0+255): count per j-tile bxe is 32*(bxe+1),
    // prefix pre[k] = 16*k*(k+1), total 1152. Compact enumeration.
    for (int s = bx; s < 1152; s += NBLK) {
      int bxe = 0;
#pragma unroll
      for (int k = 1; k < 8; ++k) bxe += (s >= 16 * k * (k + 1)) ? 1 : 0;
      const int bye = s - 16 * bxe * (bxe + 1);
      const int j0 = bxe * 256;
      const int i0 = bye * 8;
      const int j = j0 + tid;
      float Br[32];
      const float4* bp = (const float4*)(Bm + j * 32);
#pragma unroll
      for (int q = 0; q < 8; ++q) {
        float4 v = bp[q];
        Br[4 * q + 0] = v.x;
        Br[4 * q + 1] = v.y;
        Br[4 * q + 2] = v.z;
        Br[4 * q + 3] = v.w;
      }
#pragma unroll
      for (int ii = 0; ii < 8; ++ii) {
        const int i = i0 + ii;
        const float* Ar = A + i * 32;  // uniform row -> scalar loads
        float d = db;
#pragma unroll
        for (int f = 0; f < 32; ++f)
          d += fmaxf(Ar[f] + Br[f], 0.f) * wd[f];
        if (i < j) {
          float p0 = 1.0f / (1.0f + __expf(d));
          int e = i * (2 * N_NODES - 1 - i) / 2 + (j - i - 1);
          out[e] = make_float2(p0, 1.0f - p0);
        }
      }
    }
  }
}

extern "C" void kernel_launch(void* const* d_in, const int* in_sizes, int n_in,
                              void* d_out, int out_size, void* d_ws, size_t ws_size,
                              hipStream_t stream) {
  const float* x    = (const float*)d_in[0];
  const float* cent = (const float*)d_in[1];
  const float* Ws1  = (const float*)d_in[2];
  const float* Wn1  = (const float*)d_in[3];
  const float* b1   = (const float*)d_in[4];
  const float* Ws2  = (const float*)d_in[5];
  const float* Wn2  = (const float*)d_in[6];
  const float* b2   = (const float*)d_in[7];
  const float* Wm1  = (const float*)d_in[8];
  const float* bm1  = (const float*)d_in[9];
  const float* Wm2  = (const float*)d_in[10];
  const float* bm2  = (const float*)d_in[11];

  float* ws  = (float*)d_ws;
  float* n1  = ws;                      // 2048*36
  float* h1  = n1 + 2048 * N1S;         // 2048*64
  float* h1T = h1 + 2048 * 64;          // 2048*64 (column-major copy)
  float* n2  = h1T + 2048 * 64;         // 2048*64
  float* A   = n2 + 2048 * 64;          // 2048*32
  float* Bm  = A + 2048 * 32;           // 2048*32  (~2.4 MB total)
  float2* outp = (float2*)d_out;

  void* args[] = {&x, &cent, &Ws1, &Wn1, &b1, &Ws2, &Wn2, &b2,
                  &Wm1, &bm1, &Wm2, &bm2,
                  &n1, &h1, &h1T, &n2, &A, &Bm, &outp};
  hipLaunchCooperativeKernel((void*)k_fused, dim3(NBLK), dim3(256), args, 0, stream);
}

// Round 2
// 124.133 us; speedup vs baseline: 2.7587x; 2.7587x over previous
//
#include <hip/hip_runtime.h>
#include <math.h>

#define N_NODES 2048
#define N1S 36  // padded n1 row stride (16B-aligned rows)

__device__ __forceinline__ float invdeg(int j) { return j > 0 ? 1.0f / (float)j : 0.0f; }

// K1: blocks 0..31 (f = bx): per-feature node scans:
//   S = prefix of x[i,f]^2/||x_i||  -> n1[i,f] = S * x̂[i,f] * invdeg(i)
//   px[i,f]  = prefix of x[i,f]
//   pn1[i,f] = prefix of n1[i,f]
// blocks 32..287: centroid aggregate per node j -> packed n1c[j*3+..]
__global__ __launch_bounds__(256) void k_feat(const float* __restrict__ x,
                                              const float* __restrict__ cent,
                                              float* __restrict__ n1,
                                              float* __restrict__ pn1,
                                              float* __restrict__ px,
                                              float* __restrict__ n1c) {
  __shared__ float smem[6144];  // 24 KB, aliased per branch
  const int tid = threadIdx.x;
  const int bx = blockIdx.x;
  if (bx < 32) {
    float* invn_s = smem;            // 2048
    float* scS = smem + 2048;        // 256
    float* scX = smem + 2048 + 256;  // 256
    const int f = bx;
    for (int r = 0; r < 8; ++r) {
      int n = tid + 256 * r;
      const float4* xp = (const float4*)(x + n * 32);
      float s = 0.f;
#pragma unroll
      for (int q = 0; q < 8; ++q) {
        float4 v = xp[q];
        s += v.x * v.x + v.y * v.y + v.z * v.z + v.w * v.w;
      }
      invn_s[n] = rsqrtf(s);
    }
    __syncthreads();
    float sv[8], xv[8], nv[8];
    float ts_s = 0.f, ts_x = 0.f;
#pragma unroll
    for (int r = 0; r < 8; ++r) {
      int i = tid * 8 + r;
      float xf = x[i * 32 + f];
      xv[r] = xf;
      float s = xf * xf * invn_s[i];
      sv[r] = s;
      ts_s += s;
      ts_x += xf;
    }
    scS[tid] = ts_s;
    scX[tid] = ts_x;
    __syncthreads();
    for (int off = 1; off < 256; off <<= 1) {
      float vS = (tid >= off) ? scS[tid - off] : 0.f;
      float vX = (tid >= off) ? scX[tid - off] : 0.f;
      __syncthreads();
      scS[tid] += vS;
      scX[tid] += vX;
      __syncthreads();
    }
    float Ps = scS[tid] - ts_s;  // exclusive prefixes of chunk sums
    float Px = scX[tid] - ts_x;
    float ts_n = 0.f;
#pragma unroll
    for (int r = 0; r < 8; ++r) {
      int i = tid * 8 + r;
      float n1v = Ps * xv[r] * invn_s[i] * invdeg(i);
      n1[i * N1S + f] = n1v;
      px[i * 32 + f] = Px;
      nv[r] = n1v;
      ts_n += n1v;
      Ps += sv[r];
      Px += xv[r];
    }
    scS[tid] = ts_n;  // own-cell only since last barrier: safe
    __syncthreads();
    for (int off = 1; off < 256; off <<= 1) {
      float v = (tid >= off) ? scS[tid - off] : 0.f;
      __syncthreads();
      scS[tid] += v;
      __syncthreads();
    }
    float Pn = scS[tid] - ts_n;
#pragma unroll
    for (int r = 0; r < 8; ++r) {
      int i = tid * 8 + r;
      pn1[i * N1S + f] = Pn;
      Pn += nv[r];
    }
  } else {
    float* cs = smem;  // 6144 floats
    const float4* cp = (const float4*)cent;
    float4* csp = (float4*)cs;
#pragma unroll
    for (int q = 0; q < 6; ++q) csp[tid + 256 * q] = cp[tid + 256 * q];
    __syncthreads();
    const int w = (bx - 32) * 4 + (tid >> 6);  // 0..1023
    const int lane = tid & 63;
#pragma unroll
    for (int pick = 0; pick < 2; ++pick) {
      const int j = pick ? (2047 - w) : w;
      const float cj0 = cs[j * 3 + 0], cj1 = cs[j * 3 + 1], cj2 = cs[j * 3 + 2];
      float s0 = 0.f, s1 = 0.f, s2 = 0.f;
      for (int i = lane; i < j; i += 64) {
        float c0 = cs[i * 3 + 0], c1 = cs[i * 3 + 1], c2 = cs[i * 3 + 2];
        s0 += c0 * fabsf(c0 - cj0);
        s1 += c1 * fabsf(c1 - cj1);
        s2 += c2 * fabsf(c2 - cj2);
      }
#pragma unroll
      for (int d = 32; d > 0; d >>= 1) {
        s0 += __shfl_down(s0, d);
        s1 += __shfl_down(s1, d);
        s2 += __shfl_down(s2, d);
      }
      if (lane == 0) {
        float idg = invdeg(j);
        n1c[j * 3 + 0] = s0 * idg;
        n1c[j * 3 + 1] = s1 * idg;
        n1c[j * 3 + 2] = s2 * idg;
      }
    }
  }
}

// K2: wave-per-node, fused P2+P3+P4.
// Phase A: h1[n,o] and n2[n,o] via linearity (n2 = invdeg*(prefH@W1) + b1).
// Phase B: h2 via LDS handoff -> A[n,:], Bm[n,:].
__global__ __launch_bounds__(256) void k_node(
    const float* __restrict__ x, const float* __restrict__ cent,
    const float* __restrict__ n1, const float* __restrict__ pn1,
    const float* __restrict__ px, const float* __restrict__ n1c,
    const float* __restrict__ Ws1, const float* __restrict__ Wn1,
    const float* __restrict__ b1, const float* __restrict__ Ws2,
    const float* __restrict__ Wn2, const float* __restrict__ b2,
    const float* __restrict__ Wm1, const float* __restrict__ bm1,
    float* __restrict__ A, float* __restrict__ Bm) {
  __shared__ float h1s[4][64], n2s[4][64], h2s[4][32];
  const int tid = threadIdx.x;
  const int wv = tid >> 6, lane = tid & 63;
  const int n = __builtin_amdgcn_readfirstlane(blockIdx.x * 4 + wv);
  const int o = lane;
  // wave-cooperative prefix sums over j < n of cent and n1c (3+3 dims)
  float pc0 = 0.f, pc1 = 0.f, pc2 = 0.f, pq0 = 0.f, pq1 = 0.f, pq2 = 0.f;
  for (int j = lane; j < n; j += 64) {
    pc0 += cent[j * 3 + 0];
    pc1 += cent[j * 3 + 1];
    pc2 += cent[j * 3 + 2];
    pq0 += n1c[j * 3 + 0];
    pq1 += n1c[j * 3 + 1];
    pq2 += n1c[j * 3 + 2];
  }
#pragma unroll
  for (int d = 32; d > 0; d >>= 1) {
    pc0 += __shfl_xor(pc0, d);
    pc1 += __shfl_xor(pc1, d);
    pc2 += __shfl_xor(pc2, d);
    pq0 += __shfl_xor(pq0, d);
    pq1 += __shfl_xor(pq1, d);
    pq2 += __shfl_xor(pq2, d);
  }
  float acc1 = b1[o], acc2 = 0.f;
  const float4* xr = (const float4*)(x + n * 32);
  const float4* nr = (const float4*)(n1 + n * N1S);
  const float4* pxr = (const float4*)(px + n * 32);
  const float4* pnr = (const float4*)(pn1 + n * N1S);
#pragma unroll
  for (int q = 0; q < 8; ++q) {
    float4 xv = xr[q], nv = nr[q], pxv = pxr[q], pnv = pnr[q];
    {
      float ws = Ws1[(4 * q + 0) * 64 + o], wn = Wn1[(4 * q + 0) * 64 + o];
      acc1 += xv.x * ws + nv.x * wn;
      acc2 += pxv.x * ws + pnv.x * wn;
    }
    {
      float ws = Ws1[(4 * q + 1) * 64 + o], wn = Wn1[(4 * q + 1) * 64 + o];
      acc1 += xv.y * ws + nv.y * wn;
      acc2 += pxv.y * ws + pnv.y * wn;
    }
    {
      float ws = Ws1[(4 * q + 2) * 64 + o], wn = Wn1[(4 * q + 2) * 64 + o];
      acc1 += xv.z * ws + nv.z * wn;
      acc2 += pxv.z * ws + pnv.z * wn;
    }
    {
      float ws = Ws1[(4 * q + 3) * 64 + o], wn = Wn1[(4 * q + 3) * 64 + o];
      acc1 += xv.w * ws + nv.w * wn;
      acc2 += pxv.w * ws + pnv.w * wn;
    }
  }
  {
    float c0 = cent[n * 3 + 0], c1 = cent[n * 3 + 1], c2 = cent[n * 3 + 2];
    float q0 = n1c[n * 3 + 0], q1 = n1c[n * 3 + 1], q2 = n1c[n * 3 + 2];
    float ws, wn;
    ws = Ws1[32 * 64 + o]; wn = Wn1[32 * 64 + o];
    acc1 += c0 * ws + q0 * wn;
    acc2 += pc0 * ws + pq0 * wn;
    ws = Ws1[33 * 64 + o]; wn = Wn1[33 * 64 + o];
    acc1 += c1 * ws + q1 * wn;
    acc2 += pc1 * ws + pq1 * wn;
    ws = Ws1[34 * 64 + o]; wn = Wn1[34 * 64 + o];
    acc1 += c2 * ws + q2 * wn;
    acc2 += pc2 * ws + pq2 * wn;
  }
  h1s[wv][o] = acc1;
  n2s[wv][o] = invdeg(n) * acc2 + (n > 0 ? b1[o] : 0.f);
  __syncthreads();
  // Phase B (as the verified K4): both halves compute h2[oo] redundantly.
  const int oo = lane & 31, half = lane >> 5;
  float acc = b2[oo];
#pragma unroll
  for (int f2 = 0; f2 < 64; ++f2)
    acc += h1s[wv][f2] * Ws2[f2 * 32 + oo] + n2s[wv][f2] * Wn2[f2 * 32 + oo];
  h2s[wv][oo] = acc;
  __syncthreads();
  float r = half ? bm1[oo] : 0.f;
#pragma unroll
  for (int f2 = 0; f2 < 32; ++f2)
    r += h2s[wv][f2] * Wm1[(half * 32 + f2) * 32 + oo];
  if (half)
    Bm[n * 32 + oo] = r;
  else
    A[n * 32 + oo] = r;
}

// K3: per-edge head, LDS-free, logit-difference form (verified round-0 version).
__global__ __launch_bounds__(256) void k_edges(const float* __restrict__ A,
                                               const float* __restrict__ Bm,
                                               const float* __restrict__ Wm2,
                                               const float* __restrict__ bm2,
                                               float2* __restrict__ out) {
  const int tid = threadIdx.x;
  const int j0 = blockIdx.x * 256;
  const int i0 = blockIdx.y * 8;
  if (i0 >= j0 + 255) return;  // tile entirely below diagonal
  const int j = j0 + tid;
  float Br[32];
  const float4* bp = (const float4*)(Bm + j * 32);
#pragma unroll
  for (int q = 0; q < 8; ++q) {
    float4 v = bp[q];
    Br[4 * q + 0] = v.x;
    Br[4 * q + 1] = v.y;
    Br[4 * q + 2] = v.z;
    Br[4 * q + 3] = v.w;
  }
  float wd[32];
#pragma unroll
  for (int f = 0; f < 32; ++f)
    wd[f] = Wm2[f * 2 + 1] - Wm2[f * 2];  // uniform
  const float db = bm2[1] - bm2[0];
#pragma unroll
  for (int ii = 0; ii < 8; ++ii) {
    const int i = i0 + ii;
    const float* Ar = A + i * 32;  // uniform row -> scalar loads
    float d = db;
#pragma unroll
    for (int f = 0; f < 32; ++f)
      d += fmaxf(Ar[f] + Br[f], 0.f) * wd[f];
    if (i < j) {
      float p0 = 1.0f / (1.0f + __expf(d));
      int e = i * (2 * N_NODES - 1 - i) / 2 + (j - i - 1);
      out[e] = make_float2(p0, 1.0f - p0);
    }
  }
}

extern "C" void kernel_launch(void* const* d_in, const int* in_sizes, int n_in,
                              void* d_out, int out_size, void* d_ws, size_t ws_size,
                              hipStream_t stream) {
  const float* x    = (const float*)d_in[0];
  const float* cent = (const float*)d_in[1];
  const float* Ws1  = (const float*)d_in[2];
  const float* Wn1  = (const float*)d_in[3];
  const float* b1   = (const float*)d_in[4];
  const float* Ws2  = (const float*)d_in[5];
  const float* Wn2  = (const float*)d_in[6];
  const float* b2   = (const float*)d_in[7];
  const float* Wm1  = (const float*)d_in[8];
  const float* bm1  = (const float*)d_in[9];
  const float* Wm2  = (const float*)d_in[10];
  const float* bm2  = (const float*)d_in[11];

  float* ws  = (float*)d_ws;
  float* n1  = ws;                       // 2048*36
  float* pn1 = n1 + 2048 * N1S;          // 2048*36
  float* px  = pn1 + 2048 * N1S;         // 2048*32
  float* n1c = px + 2048 * 32;           // 2048*3
  float* A   = n1c + 2048 * 3;           // 2048*32
  float* Bm  = A + 2048 * 32;            // 2048*32  (~1.4 MB total)

  k_feat<<<288, 256, 0, stream>>>(x, cent, n1, pn1, px, n1c);
  k_node<<<512, 256, 0, stream>>>(x, cent, n1, pn1, px, n1c,
                                  Ws1, Wn1, b1, Ws2, Wn2, b2, Wm1, bm1, A, Bm);
  k_edges<<<dim3(8, 256), 256, 0, stream>>>(A, Bm, Wm2, bm2, (float2*)d_out);
}